// Round 7
// baseline (844.959 us; speedup 1.0000x reference)
//
#include <hip/hip_runtime.h>
#include <hip/hip_fp16.h>

#define BB 2048
#define NN 1568
#define CD 48

// ---- scalar-safe half2 pack/unpack (no local-array casts — round-3 spill lesson)
__device__ __forceinline__ unsigned packh2(float a, float b) {
    __half2 h = __floats2half2_rn(a, b);
    unsigned r; __builtin_memcpy(&r, &h, 4); return r;
}
__device__ __forceinline__ float2 uph2(unsigned v) {
    __half2 h; __builtin_memcpy(&h, &v, 4); return __half22float2(h);
}

// =================== K1: u fp16 + s1 = sum_n u (fused) ===================
// grid = 98 g x 64 bg; block 256 = bl16 x h2 x ns8. Block tile: 32 b x 16 n.
// Each thread: 2 batches (b1 = bg*32+bl, b2 = b1+16), 24 cd (h-half), 2 n.
// Every ds_read_b128 of W feeds TWO batches' FMA (halves LDS-pipe pressure vs R5).
// s1: per-thread acc -> LDS atomics (stride 49 = conflict-free banks) -> global atomics.
__global__ __launch_bounds__(256, 3)
void k1_u(const float* __restrict__ x, const float* __restrict__ W,
          __half* __restrict__ u, float* __restrict__ s1g)
{
    __shared__ float wlds[16 * 384];   // 24,576 B: [n-row][c*128 + d*8 + e]
    __shared__ float s1l[32 * 49];     // padded stride 49 -> 16 distinct banks over bl
    const int t  = threadIdx.x;
    const int bl = t & 15;
    const int h  = (t >> 4) & 1;
    const int ns = t >> 5;             // 0..7, two n each
    const int bg = blockIdx.x & 63;
    const int g  = blockIdx.x >> 6;
    const int n0 = g * 16;
    const int b1 = bg * 32 + bl;
    const int b2 = b1 + 16;

    for (int k = t; k < 32 * 49; k += 256) s1l[k] = 0.f;

    // stage W[c, n0:n0+16, :, :] -> wlds, coalesced (6 float4/thread)
#pragma unroll
    for (int k = 0; k < 6; ++k) {
        const int q = t + k * 256;
        const int c = q >> 9;
        const int j = (q >> 5) & 15;
        const int f = q & 31;
        const float4 v = *(const float4*)(W + (((size_t)(c * NN + n0 + j)) << 7) + (f << 2));
        *(float4*)(wlds + j * 384 + c * 128 + (f << 2)) = v;
    }
    __syncthreads();

    float acc[48];                     // [0:24) = b1's 24 cd, [24:48) = b2's
#pragma unroll
    for (int i = 0; i < 48; ++i) acc[i] = 0.f;

#pragma unroll
    for (int i = 0; i < 2; ++i) {
        const int nr = ns * 2 + i;
        const int n  = n0 + nr;
        const float* xp1 = x + ((size_t)b1 * NN + n) * 8;
        const float* xp2 = x + ((size_t)b2 * NN + n) * 8;
        const float4 xa1 = __ldg((const float4*)xp1), xb1 = __ldg((const float4*)(xp1 + 4));
        const float4 xa2 = __ldg((const float4*)xp2), xb2 = __ldg((const float4*)(xp2 + 4));
        __half* d1 = u + ((size_t)b1 * NN + n) * CD + h * 8;
        __half* d2 = u + ((size_t)b2 * NN + n) * CD + h * 8;

#pragma unroll
        for (int c = 0; c < 3; ++c) {
            const float* wc = wlds + nr * 384 + c * 128 + h * 64;
            uint4 p1, p2;
#pragma unroll
            for (int pp = 0; pp < 4; ++pp) {   // dd = 2pp, 2pp+1
                const float4 w0 = *(const float4*)(wc + 16 * pp);
                const float4 w1 = *(const float4*)(wc + 16 * pp + 4);
                const float4 w2 = *(const float4*)(wc + 16 * pp + 8);
                const float4 w3 = *(const float4*)(wc + 16 * pp + 12);
                const float a0 = w0.x*xa1.x + w0.y*xa1.y + w0.z*xa1.z + w0.w*xa1.w
                               + w1.x*xb1.x + w1.y*xb1.y + w1.z*xb1.z + w1.w*xb1.w;
                const float a1 = w2.x*xa1.x + w2.y*xa1.y + w2.z*xa1.z + w2.w*xa1.w
                               + w3.x*xb1.x + w3.y*xb1.y + w3.z*xb1.z + w3.w*xb1.w;
                const float q0 = w0.x*xa2.x + w0.y*xa2.y + w0.z*xa2.z + w0.w*xa2.w
                               + w1.x*xb2.x + w1.y*xb2.y + w1.z*xb2.z + w1.w*xb2.w;
                const float q1 = w2.x*xa2.x + w2.y*xa2.y + w2.z*xa2.z + w2.w*xa2.w
                               + w3.x*xb2.x + w3.y*xb2.y + w3.z*xb2.z + w3.w*xb2.w;
                acc[c*8 + 2*pp]          += a0;
                acc[c*8 + 2*pp + 1]      += a1;
                acc[24 + c*8 + 2*pp]     += q0;
                acc[24 + c*8 + 2*pp + 1] += q1;
                const unsigned v1p = packh2(a0, a1);
                const unsigned v2p = packh2(q0, q1);
                if (pp == 0) { p1.x = v1p; p2.x = v2p; }
                else if (pp == 1) { p1.y = v1p; p2.y = v2p; }
                else if (pp == 2) { p1.z = v1p; p2.z = v2p; }
                else { p1.w = v1p; p2.w = v2p; }
            }
            *(uint4*)(d1 + c * 16) = p1;
            *(uint4*)(d2 + c * 16) = p2;
        }
    }

    // s1: LDS atomic accumulate (8-way ns contention per address; banks spread by stride 49)
#pragma unroll
    for (int c = 0; c < 3; ++c) {
#pragma unroll
        for (int dd = 0; dd < 8; ++dd) {
            atomicAdd(&s1l[bl * 49 + c * 16 + h * 8 + dd], acc[c*8 + dd]);
            atomicAdd(&s1l[(bl + 16) * 49 + c * 16 + h * 8 + dd], acc[24 + c*8 + dd]);
        }
    }
    __syncthreads();
    // one coalesced global-atomic pass: 1536 values
    for (int k = t; k < 1536; k += 256) {
        const int j  = k / 48;
        const int cd = k - j * 48;
        atomicAdd(&s1g[(bg * 32 + j) * CD + cd], s1l[j * 49 + cd]);
    }
}

// =================== squash kernel: v1 = squash(s1/3), IN-PLACE ===================
// thread t owns elements (2t, 2t+1); 8 consecutive lanes cover one (b,c)'s 16 d.
__global__ __launch_bounds__(256, 4)
void k_squash(float* __restrict__ s1)
{
    const int t = blockIdx.x * 256 + threadIdx.x;   // 0 .. B*CD/2-1
    const float2 a = *(const float2*)(s1 + 2 * t);
    const float s0 = a.x * (1.0f / 3.0f), s1v = a.y * (1.0f / 3.0f);
    float q = s0 * s0 + s1v * s1v;
    q += __shfl_xor(q, 1); q += __shfl_xor(q, 2); q += __shfl_xor(q, 4);
    const float f = sqrtf(q) / (1.f + q);
    float2 o; o.x = s0 * f; o.y = s1v * f;
    *(float2*)(s1 + 2 * t) = o;
}

// =================== K2: routing, 2 passes (v1 precomputed), one block per batch ===================
__global__ __launch_bounds__(256, 4)
void k2_route(const __half* __restrict__ u, const float* __restrict__ v1,
              float* __restrict__ out)
{
    __shared__ float red[4][CD];
    __shared__ float vsh[CD];

    const int t = threadIdx.x;
    const int w = t >> 6;
    const int b = blockIdx.x;
    const __half* ub = u + (size_t)b * NN * CD;

    if (t < CD) vsh[t] = v1[b * CD + t];
    __syncthreads();

    float acc[CD];

#pragma unroll 1
    for (int pass = 1; pass <= 2; ++pass) {
        float wv[CD];
#pragma unroll
        for (int i = 0; i < CD; ++i) wv[i] = vsh[i];
#pragma unroll
        for (int i = 0; i < CD; ++i) acc[i] = 0.f;

        for (int n = t; n < NN; n += 256) {
            const uint4* p = (const uint4*)(ub + (size_t)n * CD);
            const uint4 r0 = p[0], r1 = p[1], r2 = p[2], r3 = p[3], r4 = p[4], r5 = p[5];
            const unsigned rr[24] = { r0.x,r0.y,r0.z,r0.w, r1.x,r1.y,r1.z,r1.w,
                                      r2.x,r2.y,r2.z,r2.w, r3.x,r3.y,r3.z,r3.w,
                                      r4.x,r4.y,r4.z,r4.w, r5.x,r5.y,r5.z,r5.w };
            float l0 = 0.f, l1 = 0.f, l2 = 0.f;
#pragma unroll
            for (int j = 0; j < 8; ++j) {
                const float2 f0 = uph2(rr[j]);
                const float2 f1 = uph2(rr[8 + j]);
                const float2 f2 = uph2(rr[16 + j]);
                l0 += wv[2*j]      * f0.x + wv[2*j+1]      * f0.y;
                l1 += wv[16+2*j]   * f1.x + wv[16+2*j+1]   * f1.y;
                l2 += wv[32+2*j]   * f2.x + wv[32+2*j+1]   * f2.y;
            }
            // |logit| < ~0.1 — no max-shift needed
            const float e0 = __expf(l0), e1 = __expf(l1), e2 = __expf(l2);
            const float inv = 1.f / (e0 + e1 + e2);
            const float c0 = e0 * inv, c1 = e1 * inv, c2 = e2 * inv;
#pragma unroll
            for (int j = 0; j < 8; ++j) {
                const float2 f0 = uph2(rr[j]);
                const float2 f1 = uph2(rr[8 + j]);
                const float2 f2 = uph2(rr[16 + j]);
                acc[2*j]      += c0 * f0.x;  acc[2*j+1]      += c0 * f0.y;
                acc[16+2*j]   += c1 * f1.x;  acc[16+2*j+1]   += c1 * f1.y;
                acc[32+2*j]   += c2 * f2.x;  acc[32+2*j+1]   += c2 * f2.y;
            }
        }
#pragma unroll
        for (int i = 0; i < CD; ++i) {
            float v = acc[i];
            v += __shfl_xor(v, 1); v += __shfl_xor(v, 2); v += __shfl_xor(v, 4);
            v += __shfl_xor(v, 8); v += __shfl_xor(v, 16); v += __shfl_xor(v, 32);
            acc[i] = v;
        }
        if ((t & 63) == 0) { for (int i = 0; i < CD; ++i) red[w][i] = acc[i]; }
        __syncthreads();
        if (t < CD) {
            const float s = red[0][t] + red[1][t] + red[2][t] + red[3][t];
            float q = s * s;
            q += __shfl_xor(q, 1); q += __shfl_xor(q, 2); q += __shfl_xor(q, 4); q += __shfl_xor(q, 8);
            const float v = s * sqrtf(q) / (1.f + q);
            if (pass == 1) vsh[t] = wv[t] + v;        // w2 = v1 + v2
            else           out[b * CD + t] = v;       // final
        }
        __syncthreads();
    }
}

extern "C" void kernel_launch(void* const* d_in, const int* in_sizes, int n_in,
                              void* d_out, int out_size, void* d_ws, size_t ws_size,
                              hipStream_t stream) {
    (void)in_sizes; (void)n_in; (void)out_size;
    const float* x = (const float*)d_in[0];   // (B, N, 8) fp32
    const float* W = (const float*)d_in[1];   // (1, 3, N, 16, 8) fp32
    const size_t u_bytes  = (size_t)BB * NN * CD * sizeof(__half);  // 308,281,344
    const size_t s1_bytes = (size_t)BB * CD * sizeof(float);        // 393,216
    if (ws_size < u_bytes + s1_bytes) return;   // == R1-proven footprint 308,674,560
    __half* u  = (__half*)d_ws;
    float*  s1 = (float*)((char*)d_ws + u_bytes);

    hipMemsetAsync(s1, 0, s1_bytes, stream);
    hipLaunchKernelGGL(k1_u,     dim3(98 * 64), dim3(256), 0, stream, x, W, u, s1);
    hipLaunchKernelGGL(k_squash, dim3((BB * CD / 2) / 256), dim3(256), 0, stream, s1);
    hipLaunchKernelGGL(k2_route, dim3(BB), dim3(256), 0, stream, u, s1, (float*)d_out);
}

// Round 8
// 726.159 us; speedup vs baseline: 1.1636x; 1.1636x over previous
//
#include <hip/hip_runtime.h>
#include <hip/hip_fp16.h>

#define BB 2048
#define NN 1568
#define CD 48

// ---- scalar-safe half2 pack/unpack (no local-array casts — round-3 spill lesson)
__device__ __forceinline__ unsigned packh2(float a, float b) {
    __half2 h = __floats2half2_rn(a, b);
    unsigned r; __builtin_memcpy(&r, &h, 4); return r;
}
__device__ __forceinline__ float2 uph2(unsigned v) {
    __half2 h; __builtin_memcpy(&h, &v, 4); return __half22float2(h);
}

#define RSTRIDE 52   // padded reduction stride: (52*l+4j)%32 covers all banks over 8 lanes

// =================== K1: u fp16 + s1 = sum_n u (fused, NO LDS atomics) ===================
// grid = 98 g x 64 bg; block 256 = bl16 x h2 x ns8. Block tile: 32 b x 16 n.
// Thread: 2 batches (b1, b1+16), 24 cd (h-half), 2 n. Each W ds_read feeds 2 batches.
// s1: 3-step barrier-staged tree reduction over ns (stride-52 pad, conflict-free),
// then one coalesced global-atomic pass (1536 adds, contention 98/address).
__global__ __launch_bounds__(256, 4)
void k1_u(const float* __restrict__ x, const float* __restrict__ W,
          __half* __restrict__ u, float* __restrict__ s1g)
{
    __shared__ float wlds[128 * RSTRIDE];   // 26,624 B (W staging uses first 6144 floats)
    const int t  = threadIdx.x;
    const int bl = t & 15;
    const int h  = (t >> 4) & 1;
    const int ns = t >> 5;             // 0..7, two n each
    const int bg = blockIdx.x & 63;
    const int g  = blockIdx.x >> 6;
    const int n0 = g * 16;
    const int b1 = bg * 32 + bl;
    const int b2 = b1 + 16;

    // stage W[c, n0:n0+16, :, :] -> wlds[j*384 + c*128 + d*8 + e], coalesced
#pragma unroll
    for (int k = 0; k < 6; ++k) {
        const int q = t + k * 256;
        const int c = q >> 9;
        const int j = (q >> 5) & 15;
        const int f = q & 31;
        const float4 v = *(const float4*)(W + (((size_t)(c * NN + n0 + j)) << 7) + (f << 2));
        *(float4*)(wlds + j * 384 + c * 128 + (f << 2)) = v;
    }
    __syncthreads();

    float acc[48];                     // [0:24) = b1's 24 cd, [24:48) = b2's
#pragma unroll
    for (int i = 0; i < 48; ++i) acc[i] = 0.f;

#pragma unroll
    for (int i = 0; i < 2; ++i) {
        const int nr = ns * 2 + i;
        const int n  = n0 + nr;
        const float* xp1 = x + ((size_t)b1 * NN + n) * 8;
        const float* xp2 = x + ((size_t)b2 * NN + n) * 8;
        const float4 xa1 = __ldg((const float4*)xp1), xb1 = __ldg((const float4*)(xp1 + 4));
        const float4 xa2 = __ldg((const float4*)xp2), xb2 = __ldg((const float4*)(xp2 + 4));
        __half* d1 = u + ((size_t)b1 * NN + n) * CD + h * 8;
        __half* d2 = u + ((size_t)b2 * NN + n) * CD + h * 8;

#pragma unroll
        for (int c = 0; c < 3; ++c) {
            const float* wc = wlds + nr * 384 + c * 128 + h * 64;
            uint4 p1, p2;
#pragma unroll
            for (int pp = 0; pp < 4; ++pp) {   // dd = 2pp, 2pp+1
                const float4 w0 = *(const float4*)(wc + 16 * pp);
                const float4 w1 = *(const float4*)(wc + 16 * pp + 4);
                const float4 w2 = *(const float4*)(wc + 16 * pp + 8);
                const float4 w3 = *(const float4*)(wc + 16 * pp + 12);
                const float a0 = w0.x*xa1.x + w0.y*xa1.y + w0.z*xa1.z + w0.w*xa1.w
                               + w1.x*xb1.x + w1.y*xb1.y + w1.z*xb1.z + w1.w*xb1.w;
                const float a1 = w2.x*xa1.x + w2.y*xa1.y + w2.z*xa1.z + w2.w*xa1.w
                               + w3.x*xb1.x + w3.y*xb1.y + w3.z*xb1.z + w3.w*xb1.w;
                const float q0 = w0.x*xa2.x + w0.y*xa2.y + w0.z*xa2.z + w0.w*xa2.w
                               + w1.x*xb2.x + w1.y*xb2.y + w1.z*xb2.z + w1.w*xb2.w;
                const float q1 = w2.x*xa2.x + w2.y*xa2.y + w2.z*xa2.z + w2.w*xa2.w
                               + w3.x*xb2.x + w3.y*xb2.y + w3.z*xb2.z + w3.w*xb2.w;
                acc[c*8 + 2*pp]          += a0;
                acc[c*8 + 2*pp + 1]      += a1;
                acc[24 + c*8 + 2*pp]     += q0;
                acc[24 + c*8 + 2*pp + 1] += q1;
                const unsigned v1p = packh2(a0, a1);
                const unsigned v2p = packh2(q0, q1);
                if (pp == 0) { p1.x = v1p; p2.x = v2p; }
                else if (pp == 1) { p1.y = v1p; p2.y = v2p; }
                else if (pp == 2) { p1.z = v1p; p2.z = v2p; }
                else { p1.w = v1p; p2.w = v2p; }
            }
            *(uint4*)(d1 + c * 16) = p1;
            *(uint4*)(d2 + c * 16) = p2;
        }
    }

    // ---- barrier-staged tree reduction over ns: 256 -> 128 -> 64 -> 32 threads ----
    __syncthreads();   // all W reads from wlds done; safe to reuse
#pragma unroll
    for (int step = 128; step >= 32; step >>= 1) {
        if (t >= step && t < 2 * step) {
            float* dst = wlds + (t - step) * RSTRIDE;
#pragma unroll
            for (int j = 0; j < 12; ++j) {
                float4 s;
                s.x = acc[4*j+0]; s.y = acc[4*j+1]; s.z = acc[4*j+2]; s.w = acc[4*j+3];
                *(float4*)(dst + 4 * j) = s;
            }
        }
        __syncthreads();
        if (t < step) {
            const float* src = wlds + t * RSTRIDE;
#pragma unroll
            for (int j = 0; j < 12; ++j) {
                const float4 s = *(const float4*)(src + 4 * j);
                acc[4*j+0] += s.x; acc[4*j+1] += s.y; acc[4*j+2] += s.z; acc[4*j+3] += s.w;
            }
        }
        __syncthreads();
    }

    // t < 32 holds block-level s1 for (b1: acc[0:24), b2: acc[24:48)) -> stage at stride 48
    if (t < 32) {
#pragma unroll
        for (int c = 0; c < 3; ++c) {
#pragma unroll
            for (int dd = 0; dd < 8; ++dd) {
                wlds[bl * 48 + c * 16 + h * 8 + dd]        = acc[c*8 + dd];
                wlds[(bl + 16) * 48 + c * 16 + h * 8 + dd] = acc[24 + c*8 + dd];
            }
        }
    }
    __syncthreads();
    // coalesced global-atomic pass: s1g[bg*1536 + k] += wlds[k]
    for (int k = t; k < 1536; k += 256)
        atomicAdd(&s1g[bg * 1536 + k], wlds[k]);
}

// =================== squash kernel: v1 = squash(s1/3), IN-PLACE ===================
__global__ __launch_bounds__(256, 4)
void k_squash(float* __restrict__ s1)
{
    const int t = blockIdx.x * 256 + threadIdx.x;   // 0 .. B*CD/2-1
    const float2 a = *(const float2*)(s1 + 2 * t);
    const float s0 = a.x * (1.0f / 3.0f), s1v = a.y * (1.0f / 3.0f);
    float q = s0 * s0 + s1v * s1v;
    q += __shfl_xor(q, 1); q += __shfl_xor(q, 2); q += __shfl_xor(q, 4);
    const float f = sqrtf(q) / (1.f + q);
    float2 o; o.x = s0 * f; o.y = s1v * f;
    *(float2*)(s1 + 2 * t) = o;
}

// =================== K2: routing, 2 passes, lane-pair n-split for occupancy ===================
// block 256, b = blockIdx.x. Thread: parity p = t&1 owns cd-half (per c, d in [8p,8p+8));
// pair q = t>>1 walks n with stride 128. Logits combine via shfl_xor(1).
// Registers: acc[24] + wv[24] + rr[12] -> ~78 VGPR, launch_bounds(256,5) = 20 waves/CU.
__global__ __launch_bounds__(256, 5)
void k2_route(const __half* __restrict__ u, const float* __restrict__ v1,
              float* __restrict__ out)
{
    __shared__ float red[4][2][24];
    __shared__ float vsh[CD];

    const int t = threadIdx.x;
    const int w = t >> 6;
    const int p = t & 1;
    const int q = t >> 1;
    const int b = blockIdx.x;
    const char* ub = (const char*)(u + (size_t)b * NN * CD) + p * 16;

    if (t < CD) vsh[t] = v1[b * CD + t];
    __syncthreads();

#pragma unroll 1
    for (int pass = 1; pass <= 2; ++pass) {
        float wv[24];
#pragma unroll
        for (int c = 0; c < 3; ++c)
#pragma unroll
            for (int k = 0; k < 8; ++k) wv[c*8+k] = vsh[c*16 + 8*p + k];

        float acc[24];
#pragma unroll
        for (int i = 0; i < 24; ++i) acc[i] = 0.f;

        for (int n = q; n < NN; n += 128) {
            const char* base = ub + (size_t)n * 96;
            const uint4 r0 = *(const uint4*)(base);
            const uint4 r1 = *(const uint4*)(base + 32);
            const uint4 r2 = *(const uint4*)(base + 64);
            const unsigned rr[12] = { r0.x,r0.y,r0.z,r0.w, r1.x,r1.y,r1.z,r1.w,
                                      r2.x,r2.y,r2.z,r2.w };
            float lp0 = 0.f, lp1 = 0.f, lp2 = 0.f;
#pragma unroll
            for (int j = 0; j < 4; ++j) {
                const float2 f0 = uph2(rr[j]);
                const float2 f1 = uph2(rr[4 + j]);
                const float2 f2 = uph2(rr[8 + j]);
                lp0 += wv[2*j]    * f0.x + wv[2*j+1]    * f0.y;
                lp1 += wv[8+2*j]  * f1.x + wv[8+2*j+1]  * f1.y;
                lp2 += wv[16+2*j] * f2.x + wv[16+2*j+1] * f2.y;
            }
            const float l0 = lp0 + __shfl_xor(lp0, 1);
            const float l1 = lp1 + __shfl_xor(lp1, 1);
            const float l2 = lp2 + __shfl_xor(lp2, 1);
            // |logit| < ~0.1 — no max-shift needed
            const float e0 = __expf(l0), e1 = __expf(l1), e2 = __expf(l2);
            const float inv = 1.f / (e0 + e1 + e2);
            const float c0 = e0 * inv, c1 = e1 * inv, c2 = e2 * inv;
#pragma unroll
            for (int j = 0; j < 4; ++j) {
                const float2 f0 = uph2(rr[j]);
                const float2 f1 = uph2(rr[4 + j]);
                const float2 f2 = uph2(rr[8 + j]);
                acc[2*j]      += c0 * f0.x;  acc[2*j+1]      += c0 * f0.y;
                acc[8+2*j]    += c1 * f1.x;  acc[8+2*j+1]    += c1 * f1.y;
                acc[16+2*j]   += c2 * f2.x;  acc[16+2*j+1]   += c2 * f2.y;
            }
        }
        // reduce over the 32 same-parity lanes of each wave
#pragma unroll
        for (int i = 0; i < 24; ++i) {
            float v = acc[i];
            v += __shfl_xor(v, 2); v += __shfl_xor(v, 4); v += __shfl_xor(v, 8);
            v += __shfl_xor(v, 16); v += __shfl_xor(v, 32);
            acc[i] = v;
        }
        if ((t & 63) < 2) {
#pragma unroll
            for (int i = 0; i < 24; ++i) red[w][p][i] = acc[i];
        }
        __syncthreads();
        if (t < CD) {
            const int c  = t >> 4;
            const int dd = t & 15;
            const int pp = dd >> 3;
            const int jj = c * 8 + (dd & 7);
            const float s = red[0][pp][jj] + red[1][pp][jj] + red[2][pp][jj] + red[3][pp][jj];
            float qq = s * s;
            qq += __shfl_xor(qq, 1); qq += __shfl_xor(qq, 2);
            qq += __shfl_xor(qq, 4); qq += __shfl_xor(qq, 8);
            const float v = s * sqrtf(qq) / (1.f + qq);
            if (pass == 1) vsh[t] += v;               // w2 = v1 + v2
            else           out[b * CD + t] = v;       // final
        }
        __syncthreads();
    }
}

extern "C" void kernel_launch(void* const* d_in, const int* in_sizes, int n_in,
                              void* d_out, int out_size, void* d_ws, size_t ws_size,
                              hipStream_t stream) {
    (void)in_sizes; (void)n_in; (void)out_size;
    const float* x = (const float*)d_in[0];   // (B, N, 8) fp32
    const float* W = (const float*)d_in[1];   // (1, 3, N, 16, 8) fp32
    const size_t u_bytes  = (size_t)BB * NN * CD * sizeof(__half);  // 308,281,344
    const size_t s1_bytes = (size_t)BB * CD * sizeof(float);        // 393,216
    if (ws_size < u_bytes + s1_bytes) return;   // == R1-proven footprint 308,674,560
    __half* u  = (__half*)d_ws;
    float*  s1 = (float*)((char*)d_ws + u_bytes);

    hipMemsetAsync(s1, 0, s1_bytes, stream);
    hipLaunchKernelGGL(k1_u,     dim3(98 * 64), dim3(256), 0, stream, x, W, u, s1);
    hipLaunchKernelGGL(k_squash, dim3((BB * CD / 2) / 256), dim3(256), 0, stream, s1);
    hipLaunchKernelGGL(k2_route, dim3(BB), dim3(256), 0, stream, u, s1, (float*)d_out);
}